// Round 16
// baseline (2360.636 us; speedup 1.0000x reference)
//
#include <hip/hip_runtime.h>

#define N_ROWS 8192
#define D_IN   768
#define D_SAE  24576
#define K_TOP  32
#define C_SEL  40
#define DELTA  2e-4f

typedef __attribute__((ext_vector_type(8))) short bf16x8;
typedef __attribute__((ext_vector_type(4))) float f32x4;

__device__ __forceinline__ ushort f2bf(float f) {
    const unsigned u = __float_as_uint(f);
    return (ushort)((u + 0x7FFFu + ((u >> 16) & 1u)) >> 16);
}
__device__ __forceinline__ float bf2f(ushort h) {
    return __uint_as_float(((unsigned)h) << 16);
}

#define GBM 128
#define GBN 192
#define GBK 32

// ---------------- pre-pass 1: split (x - b_dec) into hi/lo bf16 planes ----------------
__global__ __launch_bounds__(256)
void sae_cvt_x(const float* __restrict__ x, const float* __restrict__ b_dec,
               ushort* __restrict__ ahi, ushort* __restrict__ alo)
{
    const int idx = blockIdx.x * 256 + threadIdx.x;
    const int i   = idx * 4;
    const int k   = (idx % (D_IN / 4)) * 4;
    const float4 xv = *(const float4*)(&x[i]);
    const float4 bd = *(const float4*)(&b_dec[k]);
    const float e[4] = {xv.x - bd.x, xv.y - bd.y, xv.z - bd.z, xv.w - bd.w};
    ushort h[4], l[4];
#pragma unroll
    for (int j = 0; j < 4; ++j) {
        h[j] = f2bf(e[j]);
        l[j] = f2bf(e[j] - bf2f(h[j]));
    }
    *(ushort4*)(&ahi[i]) = make_ushort4(h[0], h[1], h[2], h[3]);
    *(ushort4*)(&alo[i]) = make_ushort4(l[0], l[1], l[2], l[3]);
}

// ---------------- pre-pass 2: transpose W_enc [768][24576] -> [24576][768], split hi/lo ----------------
__global__ __launch_bounds__(256)
void sae_cvt_w(const float* __restrict__ W_enc,
               ushort* __restrict__ bhi, ushort* __restrict__ blo)
{
    __shared__ float tile[32][33];
    const int n0 = blockIdx.x * 32;
    const int k0 = blockIdx.y * 32;
    const int t  = threadIdx.x;
    const int r  = t >> 3;
    const int c4 = (t & 7) * 4;
    *(float4*)(&tile[r][c4]) = *(const float4*)(&W_enc[(size_t)(k0 + r) * D_SAE + n0 + c4]);
    __syncthreads();
    ushort h[4], l[4];
#pragma unroll
    for (int j = 0; j < 4; ++j) {
        const float e = tile[c4 + j][r];
        h[j] = f2bf(e);
        l[j] = f2bf(e - bf2f(h[j]));
    }
    *(ushort4*)(&bhi[(size_t)(n0 + r) * D_IN + k0 + c4]) = make_ushort4(h[0], h[1], h[2], h[3]);
    *(ushort4*)(&blo[(size_t)(n0 + r) * D_IN + k0 + c4]) = make_ushort4(l[0], l[1], l[2], l[3]);
}

// ------- GEMM: 8 waves x (64x48) wave tile -> 48 AGPR acc, ~118 unified regs -> 16 waves/CU -------
// staging: 40 quanta, q = j*8 + wid (j<2 -> A, j>=2 -> B; compile-time split per j)
__global__ __launch_bounds__(512, 4)
void sae_encode_mfma3(const ushort* __restrict__ ahi, const ushort* __restrict__ alo,
                      const ushort* __restrict__ bhi, const ushort* __restrict__ blo,
                      const float* __restrict__ b_enc, float* __restrict__ z)
{
    __shared__ ushort A_lds[2][4][GBM][8];   // 16 KB
    __shared__ ushort B_lds[2][4][GBN][8];   // 24 KB -> 40 KB total

    const int tid  = threadIdx.x;
    const int lane = tid & 63;
    const int wid  = tid >> 6;        // 0..7
    const int wr   = wid >> 2;        // 0..1
    const int wc   = wid & 3;         // 0..3
    const int l15  = lane & 15;
    const int lc   = lane >> 4;

    const int col0  = blockIdx.y * GBN;       // row-blocks fast (L2 B-panel reuse)
    const int arow0 = blockIdx.x * GBM;
    const int row_w = arow0 + wr * 64;

    const int NT = D_IN / GBK;   // 24

    f32x4 acc[4][3];
#pragma unroll
    for (int i = 0; i < 4; ++i)
#pragma unroll
        for (int j = 0; j < 3; ++j) acc[i][j] = (f32x4){0.f, 0.f, 0.f, 0.f};

    bf16x8 s0, s1, s2, s3, s4;

#define LOADQ(J, DST) { \
        const int q = (J) * 8 + wid; \
        if ((J) < 2) { \
            const int pl = q & 1, c = (q >> 1) & 3, h = q >> 3; \
            DST = *(const bf16x8*)((pl ? alo : ahi) + (size_t)(arow0 + h * 64 + lane) * D_IN + k0s + c * 8); \
        } else { \
            const int r2 = (J) * 8 + wid - 16; \
            const int pl = r2 & 1, c = (r2 >> 1) & 3, g = r2 >> 3; \
            DST = *(const bf16x8*)((pl ? blo : bhi) + (size_t)(col0 + g * 64 + lane) * D_IN + k0s + c * 8); \
        } }

#define WRITEQ(J, SRC) { \
        const int q = (J) * 8 + wid; \
        if ((J) < 2) { \
            const int pl = q & 1, c = (q >> 1) & 3, h = q >> 3; \
            *(bf16x8*)(&A_lds[pl][c][h * 64 + lane][0]) = SRC; \
        } else { \
            const int r2 = (J) * 8 + wid - 16; \
            const int pl = r2 & 1, c = (r2 >> 1) & 3, g = r2 >> 3; \
            *(bf16x8*)(&B_lds[pl][c][g * 64 + lane][0]) = SRC; \
        } }

#define LOAD_ALL() { LOADQ(0, s0) LOADQ(1, s1) LOADQ(2, s2) LOADQ(3, s3) LOADQ(4, s4) }
#define WRITE_ALL() { WRITEQ(0, s0) WRITEQ(1, s1) WRITEQ(2, s2) WRITEQ(3, s3) WRITEQ(4, s4) }

    // prologue: load tile 0 into regs
    {
        const int k0s = 0;
        LOAD_ALL();
    }

    for (int kt = 0; kt < NT; ++kt) {
        WRITE_ALL();            // vmcnt drain for this tile's loads happens here
        __syncthreads();        // tile visible

        if (kt + 1 < NT) {
            const int k0s = (kt + 1) * GBK;
            LOAD_ALL();         // next tile's loads in flight during MFMAs
        }

        bf16x8 bh[3], bl[3];
#pragma unroll
        for (int ct = 0; ct < 3; ++ct) {
            const int n = wc * 48 + ct * 16 + l15;
            bh[ct] = *(const bf16x8*)(&B_lds[0][lc][n][0]);
            bl[ct] = *(const bf16x8*)(&B_lds[1][lc][n][0]);
        }
#pragma unroll
        for (int rt = 0; rt < 4; ++rt) {
            const int m = wr * 64 + rt * 16 + l15;
            const bf16x8 ah = *(const bf16x8*)(&A_lds[0][lc][m][0]);
            const bf16x8 al = *(const bf16x8*)(&A_lds[1][lc][m][0]);
#pragma unroll
            for (int ct = 0; ct < 3; ++ct) {
                acc[rt][ct] = __builtin_amdgcn_mfma_f32_16x16x32_bf16(ah, bh[ct], acc[rt][ct], 0, 0, 0);
                acc[rt][ct] = __builtin_amdgcn_mfma_f32_16x16x32_bf16(ah, bl[ct], acc[rt][ct], 0, 0, 0);
                acc[rt][ct] = __builtin_amdgcn_mfma_f32_16x16x32_bf16(al, bh[ct], acc[rt][ct], 0, 0, 0);
            }
        }
        __syncthreads();        // reads done before next WRITE_ALL overwrites
    }

#undef LOAD_ALL
#undef WRITE_ALL
#undef LOADQ
#undef WRITEQ

    // ---- epilogue: + b_enc, relu, store ----
#pragma unroll
    for (int ct = 0; ct < 3; ++ct) {
        const int col = col0 + wc * 48 + ct * 16 + l15;
        const float bec = b_enc[col];
#pragma unroll
        for (int rt = 0; rt < 4; ++rt) {
            const int rowb = row_w + rt * 16 + lc * 4;
#pragma unroll
            for (int r = 0; r < 4; ++r)
                z[(size_t)(rowb + r) * D_SAE + col] = fmaxf(acc[rt][ct][r] + bec, 0.f);
        }
    }
}

// ---------------- fallback GEMM (conversion in-kernel), used if ws too small ----------------
__global__ __launch_bounds__(256, 2)
void sae_encode_mfma(const float* __restrict__ x,
                     const float* __restrict__ W_enc,
                     const float* __restrict__ b_enc,
                     const float* __restrict__ b_dec,
                     float* __restrict__ z)
{
    __shared__ ushort Bs[2][4][GBN][8];

    const int tid  = threadIdx.x;
    const int lane = tid & 63;
    const int wid  = tid >> 6;
    const int wr   = wid >> 1;
    const int wc   = wid & 1;
    const int l15  = lane & 15;
    const int lc   = lane >> 4;

    const int col0  = blockIdx.x * GBN;
    const int row_w = blockIdx.y * GBM + wr * 64;

    f32x4 acc[4][6];
#pragma unroll
    for (int i = 0; i < 4; ++i)
#pragma unroll
        for (int j = 0; j < 6; ++j) acc[i][j] = (f32x4){0.f, 0.f, 0.f, 0.f};

    for (int kt = 0; kt < D_IN / GBK; ++kt) {
        const int k0 = kt * GBK;

        float bvv[3][8];
#pragma unroll
        for (int np = 0; np < 3; ++np)
#pragma unroll
            for (int it = 0; it < 8; ++it)
                bvv[np][it] = W_enc[(size_t)(k0 + wid * 8 + it) * D_SAE + col0 + np * 64 + lane];

        const float4 bd0 = *(const float4*)(&b_dec[k0 + lc * 8]);
        const float4 bd1 = *(const float4*)(&b_dec[k0 + lc * 8 + 4]);
        bf16x8 ah[4], al[4];
#pragma unroll
        for (int rt = 0; rt < 4; ++rt) {
            const size_t off = (size_t)(row_w + rt * 16 + l15) * D_IN + k0 + lc * 8;
            const float4 a0 = *(const float4*)(&x[off]);
            const float4 a1 = *(const float4*)(&x[off + 4]);
            float e[8];
            e[0] = a0.x - bd0.x; e[1] = a0.y - bd0.y; e[2] = a0.z - bd0.z; e[3] = a0.w - bd0.w;
            e[4] = a1.x - bd1.x; e[5] = a1.y - bd1.y; e[6] = a1.z - bd1.z; e[7] = a1.w - bd1.w;
#pragma unroll
            for (int j = 0; j < 8; ++j) {
                const ushort h = f2bf(e[j]);
                ah[rt][j] = (short)h;
                al[rt][j] = (short)f2bf(e[j] - bf2f(h));
            }
        }

        uint4 bh_pk[3], bl_pk[3];
#pragma unroll
        for (int np = 0; np < 3; ++np) {
            ushort h[8], l[8];
#pragma unroll
            for (int it = 0; it < 8; ++it) {
                h[it] = f2bf(bvv[np][it]);
                l[it] = f2bf(bvv[np][it] - bf2f(h[it]));
            }
            bh_pk[np] = make_uint4((unsigned)h[0] | ((unsigned)h[1] << 16),
                                   (unsigned)h[2] | ((unsigned)h[3] << 16),
                                   (unsigned)h[4] | ((unsigned)h[5] << 16),
                                   (unsigned)h[6] | ((unsigned)h[7] << 16));
            bl_pk[np] = make_uint4((unsigned)l[0] | ((unsigned)l[1] << 16),
                                   (unsigned)l[2] | ((unsigned)l[3] << 16),
                                   (unsigned)l[4] | ((unsigned)l[5] << 16),
                                   (unsigned)l[6] | ((unsigned)l[7] << 16));
        }

        __syncthreads();
#pragma unroll
        for (int np = 0; np < 3; ++np) {
            const int n = np * 64 + lane;
            *(uint4*)(&Bs[0][wid][n][0]) = bh_pk[np];
            *(uint4*)(&Bs[1][wid][n][0]) = bl_pk[np];
        }
        __syncthreads();

#pragma unroll
        for (int ct = 0; ct < 6; ++ct) {
            const int n = wc * 96 + ct * 16 + l15;
            const bf16x8 bh = *(const bf16x8*)(&Bs[0][lc][n][0]);
            const bf16x8 bl = *(const bf16x8*)(&Bs[1][lc][n][0]);
#pragma unroll
            for (int rt = 0; rt < 4; ++rt) {
                acc[rt][ct] = __builtin_amdgcn_mfma_f32_16x16x32_bf16(ah[rt], bh, acc[rt][ct], 0, 0, 0);
                acc[rt][ct] = __builtin_amdgcn_mfma_f32_16x16x32_bf16(ah[rt], bl, acc[rt][ct], 0, 0, 0);
                acc[rt][ct] = __builtin_amdgcn_mfma_f32_16x16x32_bf16(al[rt], bh, acc[rt][ct], 0, 0, 0);
            }
        }
    }

#pragma unroll
    for (int ct = 0; ct < 6; ++ct) {
        const int col = col0 + wc * 96 + ct * 16 + l15;
        const float bec = b_enc[col];
#pragma unroll
        for (int rt = 0; rt < 4; ++rt) {
            const int rowb = row_w + rt * 16 + lc * 4;
#pragma unroll
            for (int r = 0; r < 4; ++r)
                z[(size_t)(rowb + r) * D_SAE + col] = fmaxf(acc[rt][ct][r] + bec, 0.f);
        }
    }
}

// ------------- per-row: 1-pass histogram + reg-candidates, rank-select, sparsify, decode -------------
#define TB     256
#define QPT    (D_SAE / 4 / TB)   // 24
#define HB     2048
#define NCOPY  2
#define BNDCAP 248
#define POOLN  288                // C_SEL + BNDCAP
#define NCAND  6
#define NEGF   -1e30f
#define BADIDX (1 << 30)

__global__ __launch_bounds__(TB, 4)
void sae_topk_decode(float* __restrict__ z,
                     const float* __restrict__ x,
                     const float* __restrict__ W_enc,
                     const float* __restrict__ b_enc,
                     const float* __restrict__ W_dec,
                     const float* __restrict__ b_dec,
                     float* __restrict__ x_rec)
{
    __shared__ int    hist[NCOPY * HB];
    __shared__ int    sufx[TB];
    __shared__ float  poolv[POOLN];
    __shared__ int    pooli[POOLN];
    __shared__ float  selv[C_SEL];
    __shared__ int    seli[C_SEL];
    __shared__ float  xrow[D_IN];
    __shared__ double cand[C_SEL];
    __shared__ int    shB, shChi;
    __shared__ int    nDef, nBnd, nFail;

    const int row = blockIdx.x;
    const int t   = threadIdx.x;
    const int w   = t >> 6;
    float* zr = z + (size_t)row * D_SAE;

    for (int i = t; i < NCOPY * HB; i += TB) hist[i] = 0;
    if (t == 0) { nDef = 0; nBnd = 0; nFail = 0; }
    __syncthreads();

    float cv[NCAND]; int ci[NCAND];
#pragma unroll
    for (int j = 0; j < NCAND; ++j) { cv[j] = NEGF; ci[j] = BADIDX; }
    {
        int* hw = &hist[(w >> 1) * HB];
        int zc = 0;
        for (int i0 = 0; i0 < QPT; i0 += 8) {
            f32x4 va[8];
#pragma unroll
            for (int u2 = 0; u2 < 8; ++u2)
                va[u2] = __builtin_nontemporal_load((const f32x4*)(&zr[(size_t)(t + (i0 + u2) * TB) * 4]));
#pragma unroll
            for (int u2 = 0; u2 < 8; ++u2) {
                const int base = (t + (i0 + u2) * TB) * 4;
#define PROC(f, o) { \
        const unsigned uu = __float_as_uint(f); \
        if (uu) atomicAdd(&hw[uu >> 20], 1); else ++zc; \
        const bool b0 = (f) > cv[0]; const bool b1 = (f) > cv[1]; const bool b2 = (f) > cv[2]; \
        const bool b3 = (f) > cv[3]; const bool b4 = (f) > cv[4]; const bool b5 = (f) > cv[5]; \
        if (b5) { \
            cv[5] = b4 ? cv[4] : (f);        ci[5] = b4 ? ci[4] : (base + o); \
            if (b4) { cv[4] = b3 ? cv[3] : (f); ci[4] = b3 ? ci[3] : (base + o); } \
            if (b3) { cv[3] = b2 ? cv[2] : (f); ci[3] = b2 ? ci[2] : (base + o); } \
            if (b2) { cv[2] = b1 ? cv[1] : (f); ci[2] = b1 ? ci[1] : (base + o); } \
            if (b1) { cv[1] = b0 ? cv[0] : (f); ci[1] = b0 ? ci[0] : (base + o); } \
            if (b0) { cv[0] = (f); ci[0] = (base + o); } \
        } }
                PROC(va[u2][0], 0) PROC(va[u2][1], 1) PROC(va[u2][2], 2) PROC(va[u2][3], 3)
#undef PROC
            }
        }
        if (zc) atomicAdd(&hw[0], zc);
    }
    __syncthreads();

    int cnt8[8]; int tot = 0;
#pragma unroll
    for (int j = 0; j < 8; ++j) {
        const int b = t * 8 + j;
        const int c = hist[b] + hist[HB + b];
        cnt8[j] = c; tot += c;
    }
    sufx[t] = tot;
    __syncthreads();
    for (int off = 1; off < TB; off <<= 1) {
        const int a = sufx[t];
        const int b = (t + off < TB) ? sufx[t + off] : 0;
        __syncthreads();
        sufx[t] = a + b;
        __syncthreads();
    }
    {
        int run = (t + 1 < TB) ? sufx[t + 1] : 0;
#pragma unroll
        for (int j = 7; j >= 0; --j) {
            const int c = cnt8[j];
            if (run < C_SEL && run + c >= C_SEL) { shB = t * 8 + j; shChi = run; }
            run += c;
        }
    }
    __syncthreads();
    const int B = shB;

    if (cv[NCAND - 1] > 0.f && (int)(__float_as_uint(cv[NCAND - 1]) >> 20) >= B) nFail = 1;
    __syncthreads();

    if (!nFail) {
#pragma unroll
        for (int j = 0; j < NCAND; ++j) {
            if (cv[j] > 0.f) {
                const int bk = (int)(__float_as_uint(cv[j]) >> 20);
                if (bk > B) {
                    const int p = atomicAdd(&nDef, 1);
                    poolv[p] = cv[j]; pooli[p] = ci[j];
                } else if (bk == B) {
                    const int p = atomicAdd(&nBnd, 1);
                    if (p < BNDCAP) { poolv[C_SEL + p] = cv[j]; pooli[C_SEL + p] = ci[j]; }
                }
            }
        }
    } else {
        for (int i = 0; i < QPT; ++i) {
            const float4 v = *(const float4*)(&zr[(size_t)(t + i * TB) * 4]);
            const int base = (t + i * TB) * 4;
#define COL(f, o) { const unsigned uu = __float_as_uint(f); if (uu) { const int bk = (int)(uu >> 20); \
            if (bk > B) { const int p = atomicAdd(&nDef, 1); poolv[p] = (f); pooli[p] = base + o; } \
            else if (bk == B) { const int p = atomicAdd(&nBnd, 1); if (p < BNDCAP) { poolv[C_SEL + p] = (f); pooli[C_SEL + p] = base + o; } } } }
            COL(v.x, 0) COL(v.y, 1) COL(v.z, 2) COL(v.w, 3)
#undef COL
        }
    }
    __syncthreads();

    {
        const int ndef  = nDef;
        const int nbndc = (nBnd < BNDCAP) ? nBnd : BNDCAP;
        for (int i = t; i < POOLN; i += TB)
            if (!(i < ndef) && !(i >= C_SEL && i < C_SEL + nbndc)) { poolv[i] = NEGF; pooli[i] = BADIDX; }
        if (t < C_SEL) { selv[t] = NEGF; seli[t] = BADIDX; }
    }
    __syncthreads();

    for (int e = t; e < POOLN; e += TB) {
        const float mv = poolv[e]; const int mi = pooli[e];
        int rank = 0;
        for (int j = 0; j < POOLN; ++j) {
            const float vj = poolv[j]; const int ij = pooli[j];
            if (vj > mv || (vj == mv && ij < mi)) ++rank;
        }
        if (rank < C_SEL && mi != BADIDX) { selv[rank] = mv; seli[rank] = mi; }
    }
    __syncthreads();

    if (selv[K_TOP - 1] - selv[K_TOP] < DELTA) {
        const int l = t & 63;
        for (int k = t; k < D_IN; k += TB) xrow[k] = x[(size_t)row * D_IN + k] - b_dec[k];
        __syncthreads();
        for (int j = w; j < C_SEL; j += 4) {
            const int c = seli[j];
            if (c < D_SAE) {
                double acc = 0.0;
#pragma unroll
                for (int q = 0; q < D_IN / 64; ++q) {
                    const int k = l + q * 64;
                    acc = fma((double)xrow[k], (double)W_enc[(size_t)k * D_SAE + c], acc);
                }
#pragma unroll
                for (int off = 32; off > 0; off >>= 1) acc += __shfl_down(acc, off);
                if (l == 0) {
                    const double vv = acc + (double)b_enc[c];
                    cand[j] = vv > 0.0 ? vv : 0.0;
                }
            } else if (l == 0) cand[j] = -1e300;
        }
        __syncthreads();
        if (t == 0) {
            bool used[C_SEL]; float nv[K_TOP]; int ni[K_TOP];
            for (int j = 0; j < C_SEL; ++j) used[j] = false;
            for (int s = 0; s < K_TOP; ++s) {
                int bj = -1; double bvv = 0.0; int bidx = 0;
                for (int j = 0; j < C_SEL; ++j) {
                    if (used[j]) continue;
                    const double v = cand[j]; const int idx = seli[j];
                    if (bj < 0 || v > bvv || (v == bvv && idx < bidx)) { bj = j; bvv = v; bidx = idx; }
                }
                used[bj] = true; nv[s] = (float)bvv; ni[s] = bidx;
            }
            for (int s = 0; s < K_TOP; ++s) { selv[s] = nv[s]; seli[s] = ni[s]; }
        }
        __syncthreads();
    }

    {
        const f32x4 z4 = (f32x4){0.f, 0.f, 0.f, 0.f};
        for (int i = 0; i < QPT; ++i)
            __builtin_nontemporal_store(z4, (f32x4*)(&zr[(size_t)(t + i * TB) * 4]));
    }
    __syncthreads();
    if (t < K_TOP && seli[t] < D_SAE) zr[seli[t]] = selv[t];

    float a0 = b_dec[t], a1 = b_dec[t + 256], a2 = b_dec[t + 512];
#pragma unroll 8
    for (int s = 0; s < K_TOP; ++s) {
        if (seli[s] < D_SAE) {
            const float v = selv[s];
            const float* wd = W_dec + (size_t)seli[s] * D_IN;
            a0 = fmaf(v, wd[t],       a0);
            a1 = fmaf(v, wd[t + 256], a1);
            a2 = fmaf(v, wd[t + 512], a2);
        }
    }
    float* xr = x_rec + (size_t)row * D_IN;
    xr[t] = a0; xr[t + 256] = a1; xr[t + 512] = a2;
}

extern "C" void kernel_launch(void* const* d_in, const int* in_sizes, int n_in,
                              void* d_out, int out_size, void* d_ws, size_t ws_size,
                              hipStream_t stream)
{
    const float* x     = (const float*)d_in[0];
    const float* W_enc = (const float*)d_in[1];
    const float* b_enc = (const float*)d_in[2];
    const float* W_dec = (const float*)d_in[3];
    const float* b_dec = (const float*)d_in[4];

    float* out   = (float*)d_out;
    float* x_rec = out;
    float* z     = out + (size_t)N_ROWS * D_IN;

    const size_t nA = (size_t)N_ROWS * D_IN;
    const size_t nB = (size_t)D_SAE * D_IN;
    const size_t need = (2 * nA + 2 * nB) * sizeof(ushort);

    if (ws_size >= need) {
        ushort* ahi = (ushort*)d_ws;
        ushort* alo = ahi + nA;
        ushort* bhi = alo + nA;
        ushort* blo = bhi + nB;
        sae_cvt_x<<<(int)(nA / 4 / 256), 256, 0, stream>>>(x, b_dec, ahi, alo);
        sae_cvt_w<<<dim3(D_SAE / 32, D_IN / 32), 256, 0, stream>>>(W_enc, bhi, blo);
        dim3 g1(N_ROWS / GBM, D_SAE / GBN);    // 64 x 128, row-blocks fast
        sae_encode_mfma3<<<g1, 512, 0, stream>>>(ahi, alo, bhi, blo, b_enc, z);
    } else {
        dim3 g0(D_SAE / GBN, N_ROWS / GBM);
        sae_encode_mfma<<<g0, 256, 0, stream>>>(x, W_enc, b_enc, b_dec, z);
    }
    sae_topk_decode<<<N_ROWS, TB, 0, stream>>>(z, x, W_enc, b_enc, W_dec, b_dec, x_rec);
}

// Round 17
// 2130.405 us; speedup vs baseline: 1.1081x; 1.1081x over previous
//
#include <hip/hip_runtime.h>

#define N_ROWS 8192
#define D_IN   768
#define D_SAE  24576
#define K_TOP  32
#define C_SEL  40
#define DELTA  2e-4f

typedef __attribute__((ext_vector_type(8))) short bf16x8;
typedef __attribute__((ext_vector_type(4))) float f32x4;

__device__ __forceinline__ ushort f2bf(float f) {
    const unsigned u = __float_as_uint(f);
    return (ushort)((u + 0x7FFFu + ((u >> 16) & 1u)) >> 16);
}
__device__ __forceinline__ float bf2f(ushort h) {
    return __uint_as_float(((unsigned)h) << 16);
}

#define GBM 128
#define GBN 192
#define GBK 32

// ---------------- pre-pass 1: split (x - b_dec) into hi/lo bf16 planes ----------------
__global__ __launch_bounds__(256)
void sae_cvt_x(const float* __restrict__ x, const float* __restrict__ b_dec,
               ushort* __restrict__ ahi, ushort* __restrict__ alo)
{
    const int idx = blockIdx.x * 256 + threadIdx.x;
    const int i   = idx * 4;
    const int k   = (idx % (D_IN / 4)) * 4;
    const float4 xv = *(const float4*)(&x[i]);
    const float4 bd = *(const float4*)(&b_dec[k]);
    const float e[4] = {xv.x - bd.x, xv.y - bd.y, xv.z - bd.z, xv.w - bd.w};
    ushort h[4], l[4];
#pragma unroll
    for (int j = 0; j < 4; ++j) {
        h[j] = f2bf(e[j]);
        l[j] = f2bf(e[j] - bf2f(h[j]));
    }
    *(ushort4*)(&ahi[i]) = make_ushort4(h[0], h[1], h[2], h[3]);
    *(ushort4*)(&alo[i]) = make_ushort4(l[0], l[1], l[2], l[3]);
}

// ---------------- pre-pass 2: transpose W_enc [768][24576] -> [24576][768], split hi/lo ----------------
__global__ __launch_bounds__(256)
void sae_cvt_w(const float* __restrict__ W_enc,
               ushort* __restrict__ bhi, ushort* __restrict__ blo)
{
    __shared__ float tile[32][33];
    const int n0 = blockIdx.x * 32;
    const int k0 = blockIdx.y * 32;
    const int t  = threadIdx.x;
    const int r  = t >> 3;
    const int c4 = (t & 7) * 4;
    *(float4*)(&tile[r][c4]) = *(const float4*)(&W_enc[(size_t)(k0 + r) * D_SAE + n0 + c4]);
    __syncthreads();
    ushort h[4], l[4];
#pragma unroll
    for (int j = 0; j < 4; ++j) {
        const float e = tile[c4 + j][r];
        h[j] = f2bf(e);
        l[j] = f2bf(e - bf2f(h[j]));
    }
    *(ushort4*)(&bhi[(size_t)(n0 + r) * D_IN + k0 + c4]) = make_ushort4(h[0], h[1], h[2], h[3]);
    *(ushort4*)(&blo[(size_t)(n0 + r) * D_IN + k0 + c4]) = make_ushort4(l[0], l[1], l[2], l[3]);
}

// ------- GEMM: pre-split operands, SINGLE 40KB LDS buffer, reg-staged, (256,2) -------
// (R15 verified: 1373 us, VGPR=104, no spill. LDS-BW-bound at ~30% MfmaUtil; 64x96
//  wave tile is optimal for the 96-AGPR budget -- do not shrink (R16: worse).)
__global__ __launch_bounds__(256, 2)
void sae_encode_mfma3(const ushort* __restrict__ ahi, const ushort* __restrict__ alo,
                      const ushort* __restrict__ bhi, const ushort* __restrict__ blo,
                      const float* __restrict__ b_enc, float* __restrict__ z)
{
    __shared__ ushort A_lds[2][4][GBM][8];   // 16 KB
    __shared__ ushort B_lds[2][4][GBN][8];   // 24 KB -> 40 KB total

    const int tid  = threadIdx.x;
    const int lane = tid & 63;
    const int wid  = tid >> 6;
    const int wr   = wid >> 1;
    const int wc   = wid & 1;
    const int l15  = lane & 15;
    const int lc   = lane >> 4;

    const int col0  = blockIdx.y * GBN;       // row-blocks fast (L2 B-panel reuse)
    const int arow0 = blockIdx.x * GBM;
    const int row_w = arow0 + wr * 64;

    const int NT = D_IN / GBK;   // 24

    f32x4 acc[4][6];
#pragma unroll
    for (int i = 0; i < 4; ++i)
#pragma unroll
        for (int j = 0; j < 6; ++j) acc[i][j] = (f32x4){0.f, 0.f, 0.f, 0.f};

    bf16x8 s0, s1, s2, s3, s4, s5, s6, s7, s8, s9;

#define LOADQ(J, DST) { \
        const int q = (J) * 4 + wid; \
        if ((J) < 4) { \
            const int pl = q & 1, c = (q >> 1) & 3, h = q >> 3; \
            DST = *(const bf16x8*)((pl ? alo : ahi) + (size_t)(arow0 + h * 64 + lane) * D_IN + k0s + c * 8); \
        } else { \
            const int r2 = q - 16; \
            const int pl = r2 & 1, c = (r2 >> 1) & 3, g = r2 >> 3; \
            DST = *(const bf16x8*)((pl ? blo : bhi) + (size_t)(col0 + g * 64 + lane) * D_IN + k0s + c * 8); \
        } }

#define WRITEQ(J, SRC) { \
        const int q = (J) * 4 + wid; \
        if ((J) < 4) { \
            const int pl = q & 1, c = (q >> 1) & 3, h = q >> 3; \
            *(bf16x8*)(&A_lds[pl][c][h * 64 + lane][0]) = SRC; \
        } else { \
            const int r2 = q - 16; \
            const int pl = r2 & 1, c = (r2 >> 1) & 3, g = r2 >> 3; \
            *(bf16x8*)(&B_lds[pl][c][g * 64 + lane][0]) = SRC; \
        } }

#define LOAD_ALL() { LOADQ(0, s0) LOADQ(1, s1) LOADQ(2, s2) LOADQ(3, s3) LOADQ(4, s4) \
                     LOADQ(5, s5) LOADQ(6, s6) LOADQ(7, s7) LOADQ(8, s8) LOADQ(9, s9) }
#define WRITE_ALL() { WRITEQ(0, s0) WRITEQ(1, s1) WRITEQ(2, s2) WRITEQ(3, s3) WRITEQ(4, s4) \
                      WRITEQ(5, s5) WRITEQ(6, s6) WRITEQ(7, s7) WRITEQ(8, s8) WRITEQ(9, s9) }

    // prologue: load tile 0 into regs
    {
        const int k0s = 0;
        LOAD_ALL();
    }

    for (int kt = 0; kt < NT; ++kt) {
        WRITE_ALL();            // vmcnt drain for this tile's loads happens here
        __syncthreads();        // tile visible

        if (kt + 1 < NT) {
            const int k0s = (kt + 1) * GBK;
            LOAD_ALL();         // issue next tile's loads; in flight during MFMAs
        }

        bf16x8 bh[6], bl[6];
#pragma unroll
        for (int ct = 0; ct < 6; ++ct) {
            const int n = wc * 96 + ct * 16 + l15;
            bh[ct] = *(const bf16x8*)(&B_lds[0][lc][n][0]);
            bl[ct] = *(const bf16x8*)(&B_lds[1][lc][n][0]);
        }
#pragma unroll
        for (int rt = 0; rt < 4; ++rt) {
            const int m = wr * 64 + rt * 16 + l15;
            const bf16x8 ah = *(const bf16x8*)(&A_lds[0][lc][m][0]);
            const bf16x8 al = *(const bf16x8*)(&A_lds[1][lc][m][0]);
#pragma unroll
            for (int ct = 0; ct < 6; ++ct) {
                acc[rt][ct] = __builtin_amdgcn_mfma_f32_16x16x32_bf16(ah, bh[ct], acc[rt][ct], 0, 0, 0);
                acc[rt][ct] = __builtin_amdgcn_mfma_f32_16x16x32_bf16(ah, bl[ct], acc[rt][ct], 0, 0, 0);
                acc[rt][ct] = __builtin_amdgcn_mfma_f32_16x16x32_bf16(al, bh[ct], acc[rt][ct], 0, 0, 0);
            }
        }
        __syncthreads();        // reads done before next WRITE_ALL overwrites
    }

#undef LOAD_ALL
#undef WRITE_ALL
#undef LOADQ
#undef WRITEQ

    // ---- epilogue: + b_enc, relu, store ----
#pragma unroll
    for (int ct = 0; ct < 6; ++ct) {
        const int col = col0 + wc * 96 + ct * 16 + l15;
        const float bec = b_enc[col];
#pragma unroll
        for (int rt = 0; rt < 4; ++rt) {
            const int rowb = row_w + rt * 16 + lc * 4;
#pragma unroll
            for (int r = 0; r < 4; ++r)
                z[(size_t)(rowb + r) * D_SAE + col] = fmaxf(acc[rt][ct][r] + bec, 0.f);
        }
    }
}

// ---------------- fallback GEMM (conversion in-kernel), used if ws too small ----------------
__global__ __launch_bounds__(256, 2)
void sae_encode_mfma(const float* __restrict__ x,
                     const float* __restrict__ W_enc,
                     const float* __restrict__ b_enc,
                     const float* __restrict__ b_dec,
                     float* __restrict__ z)
{
    __shared__ ushort Bs[2][4][GBN][8];

    const int tid  = threadIdx.x;
    const int lane = tid & 63;
    const int wid  = tid >> 6;
    const int wr   = wid >> 1;
    const int wc   = wid & 1;
    const int l15  = lane & 15;
    const int lc   = lane >> 4;

    const int col0  = blockIdx.x * GBN;
    const int row_w = blockIdx.y * GBM + wr * 64;

    f32x4 acc[4][6];
#pragma unroll
    for (int i = 0; i < 4; ++i)
#pragma unroll
        for (int j = 0; j < 6; ++j) acc[i][j] = (f32x4){0.f, 0.f, 0.f, 0.f};

    for (int kt = 0; kt < D_IN / GBK; ++kt) {
        const int k0 = kt * GBK;

        float bvv[3][8];
#pragma unroll
        for (int np = 0; np < 3; ++np)
#pragma unroll
            for (int it = 0; it < 8; ++it)
                bvv[np][it] = W_enc[(size_t)(k0 + wid * 8 + it) * D_SAE + col0 + np * 64 + lane];

        const float4 bd0 = *(const float4*)(&b_dec[k0 + lc * 8]);
        const float4 bd1 = *(const float4*)(&b_dec[k0 + lc * 8 + 4]);
        bf16x8 ah[4], al[4];
#pragma unroll
        for (int rt = 0; rt < 4; ++rt) {
            const size_t off = (size_t)(row_w + rt * 16 + l15) * D_IN + k0 + lc * 8;
            const float4 a0 = *(const float4*)(&x[off]);
            const float4 a1 = *(const float4*)(&x[off + 4]);
            float e[8];
            e[0] = a0.x - bd0.x; e[1] = a0.y - bd0.y; e[2] = a0.z - bd0.z; e[3] = a0.w - bd0.w;
            e[4] = a1.x - bd1.x; e[5] = a1.y - bd1.y; e[6] = a1.z - bd1.z; e[7] = a1.w - bd1.w;
#pragma unroll
            for (int j = 0; j < 8; ++j) {
                const ushort h = f2bf(e[j]);
                ah[rt][j] = (short)h;
                al[rt][j] = (short)f2bf(e[j] - bf2f(h));
            }
        }

        uint4 bh_pk[3], bl_pk[3];
#pragma unroll
        for (int np = 0; np < 3; ++np) {
            ushort h[8], l[8];
#pragma unroll
            for (int it = 0; it < 8; ++it) {
                h[it] = f2bf(bvv[np][it]);
                l[it] = f2bf(bvv[np][it] - bf2f(h[it]));
            }
            bh_pk[np] = make_uint4((unsigned)h[0] | ((unsigned)h[1] << 16),
                                   (unsigned)h[2] | ((unsigned)h[3] << 16),
                                   (unsigned)h[4] | ((unsigned)h[5] << 16),
                                   (unsigned)h[6] | ((unsigned)h[7] << 16));
            bl_pk[np] = make_uint4((unsigned)l[0] | ((unsigned)l[1] << 16),
                                   (unsigned)l[2] | ((unsigned)l[3] << 16),
                                   (unsigned)l[4] | ((unsigned)l[5] << 16),
                                   (unsigned)l[6] | ((unsigned)l[7] << 16));
        }

        __syncthreads();
#pragma unroll
        for (int np = 0; np < 3; ++np) {
            const int n = np * 64 + lane;
            *(uint4*)(&Bs[0][wid][n][0]) = bh_pk[np];
            *(uint4*)(&Bs[1][wid][n][0]) = bl_pk[np];
        }
        __syncthreads();

#pragma unroll
        for (int ct = 0; ct < 6; ++ct) {
            const int n = wc * 96 + ct * 16 + l15;
            const bf16x8 bh = *(const bf16x8*)(&Bs[0][lc][n][0]);
            const bf16x8 bl = *(const bf16x8*)(&Bs[1][lc][n][0]);
#pragma unroll
            for (int rt = 0; rt < 4; ++rt) {
                acc[rt][ct] = __builtin_amdgcn_mfma_f32_16x16x32_bf16(ah[rt], bh, acc[rt][ct], 0, 0, 0);
                acc[rt][ct] = __builtin_amdgcn_mfma_f32_16x16x32_bf16(ah[rt], bl, acc[rt][ct], 0, 0, 0);
                acc[rt][ct] = __builtin_amdgcn_mfma_f32_16x16x32_bf16(al[rt], bh, acc[rt][ct], 0, 0, 0);
            }
        }
    }

#pragma unroll
    for (int ct = 0; ct < 6; ++ct) {
        const int col = col0 + wc * 96 + ct * 16 + l15;
        const float bec = b_enc[col];
#pragma unroll
        for (int rt = 0; rt < 4; ++rt) {
            const int rowb = row_w + rt * 16 + lc * 4;
#pragma unroll
            for (int r = 0; r < 4; ++r)
                z[(size_t)(rowb + r) * D_SAE + col] = fmaxf(acc[rt][ct][r] + bec, 0.f);
        }
    }
}

// ------- per-row: candidate-only histogram (64x fewer atomics), rank-select, sparsify, decode -------
#define TB     256
#define QPT    (D_SAE / 4 / TB)   // 24
#define HB     2048
#define NCOPY  2
#define BNDCAP 248
#define POOLN  288                // C_SEL + BNDCAP
#define NCAND  6
#define NEGF   -1e30f
#define BADIDX (1 << 30)

__global__ __launch_bounds__(TB, 4)
void sae_topk_decode(float* __restrict__ z,
                     const float* __restrict__ x,
                     const float* __restrict__ W_enc,
                     const float* __restrict__ b_enc,
                     const float* __restrict__ W_dec,
                     const float* __restrict__ b_dec,
                     float* __restrict__ x_rec)
{
    __shared__ int    hist[NCOPY * HB];   // 16 KB
    __shared__ int    sufx[TB];
    __shared__ float  poolv[POOLN];
    __shared__ int    pooli[POOLN];
    __shared__ float  selv[C_SEL];
    __shared__ int    seli[C_SEL];
    __shared__ float  xrow[D_IN];
    __shared__ double cand[C_SEL];
    __shared__ int    shB;
    __shared__ int    nDef, nBnd, nFail;

    const int row = blockIdx.x;
    const int t   = threadIdx.x;
    const int w   = t >> 6;
    float* zr = z + (size_t)row * D_SAE;
    int* hw = &hist[(w >> 1) * HB];

    for (int i = t; i < NCOPY * HB; i += TB) hist[i] = 0;
    if (t == 0) { nDef = 0; nBnd = 0; nFail = 0; }
    __syncthreads();

    // ---- phase 1: single streaming read; per-thread top-6 candidates (NO atomics) ----
    float cv[NCAND]; int ci[NCAND];
#pragma unroll
    for (int j = 0; j < NCAND; ++j) { cv[j] = NEGF; ci[j] = BADIDX; }
    {
        for (int i0 = 0; i0 < QPT; i0 += 8) {
            f32x4 va[8];
#pragma unroll
            for (int u2 = 0; u2 < 8; ++u2)
                va[u2] = __builtin_nontemporal_load((const f32x4*)(&zr[(size_t)(t + (i0 + u2) * TB) * 4]));
#pragma unroll
            for (int u2 = 0; u2 < 8; ++u2) {
                const int base = (t + (i0 + u2) * TB) * 4;
#define PROC(f, o) { \
        const bool b0 = (f) > cv[0]; const bool b1 = (f) > cv[1]; const bool b2 = (f) > cv[2]; \
        const bool b3 = (f) > cv[3]; const bool b4 = (f) > cv[4]; const bool b5 = (f) > cv[5]; \
        if (b5) { \
            cv[5] = b4 ? cv[4] : (f);        ci[5] = b4 ? ci[4] : (base + o); \
            if (b4) { cv[4] = b3 ? cv[3] : (f); ci[4] = b3 ? ci[3] : (base + o); } \
            if (b3) { cv[3] = b2 ? cv[2] : (f); ci[3] = b2 ? ci[2] : (base + o); } \
            if (b2) { cv[2] = b1 ? cv[1] : (f); ci[2] = b1 ? ci[1] : (base + o); } \
            if (b1) { cv[1] = b0 ? cv[0] : (f); ci[1] = b0 ? ci[0] : (base + o); } \
            if (b0) { cv[0] = (f); ci[0] = (base + o); } \
        } }
                PROC(va[u2][0], 0) PROC(va[u2][1], 1) PROC(va[u2][2], 2) PROC(va[u2][3], 3)
#undef PROC
            }
        }
    }

    // ---- phase 2: histogram the 6 candidates per thread (1536 atomics vs 98304) ----
#pragma unroll
    for (int j = 0; j < NCAND; ++j)
        atomicAdd(&hw[__float_as_uint(cv[j]) >> 20], 1);
    __syncthreads();

    // ---- find threshold bucket B over candidate counts ----
    {
        int cnt8[8]; int tot = 0;
#pragma unroll
        for (int j = 0; j < 8; ++j) {
            const int b = t * 8 + j;
            const int c = hist[b] + hist[HB + b];
            cnt8[j] = c; tot += c;
        }
        sufx[t] = tot;
        __syncthreads();
        for (int off = 1; off < TB; off <<= 1) {
            const int a = sufx[t];
            const int b = (t + off < TB) ? sufx[t + off] : 0;
            __syncthreads();
            sufx[t] = a + b;
            __syncthreads();
        }
        int run = (t + 1 < TB) ? sufx[t + 1] : 0;
#pragma unroll
        for (int j = 7; j >= 0; --j) {
            const int c = cnt8[j];
            if (run < C_SEL && run + c >= C_SEL) shB = t * 8 + j;
            run += c;
        }
    }
    __syncthreads();

    // ---- fail check: 6th candidate qualifies -> pool may be deficient AND B may be wrong ----
    if (cv[NCAND - 1] > 0.f && (int)(__float_as_uint(cv[NCAND - 1]) >> 20) >= shB) nFail = 1;
    __syncthreads();
    const bool fail = (nFail != 0);

    if (fail) {
        // rare (~1e-6/row): rebuild FULL histogram from global, recompute B
        for (int i = t; i < NCOPY * HB; i += TB) hist[i] = 0;
        __syncthreads();
        for (int i = 0; i < QPT; ++i) {
            const float4 v = *(const float4*)(&zr[(size_t)(t + i * TB) * 4]);
            atomicAdd(&hw[__float_as_uint(v.x) >> 20], 1);
            atomicAdd(&hw[__float_as_uint(v.y) >> 20], 1);
            atomicAdd(&hw[__float_as_uint(v.z) >> 20], 1);
            atomicAdd(&hw[__float_as_uint(v.w) >> 20], 1);
        }
        __syncthreads();
        int cnt8[8]; int tot = 0;
#pragma unroll
        for (int j = 0; j < 8; ++j) {
            const int b = t * 8 + j;
            const int c = hist[b] + hist[HB + b];
            cnt8[j] = c; tot += c;
        }
        sufx[t] = tot;
        __syncthreads();
        for (int off = 1; off < TB; off <<= 1) {
            const int a = sufx[t];
            const int b = (t + off < TB) ? sufx[t + off] : 0;
            __syncthreads();
            sufx[t] = a + b;
            __syncthreads();
        }
        int run = (t + 1 < TB) ? sufx[t + 1] : 0;
#pragma unroll
        for (int j = 7; j >= 0; --j) {
            const int c = cnt8[j];
            if (run < C_SEL && run + c >= C_SEL) shB = t * 8 + j;
            run += c;
        }
        __syncthreads();
    }
    const int B = shB;

    // ---- collect: defs (bucket > B) and boundary (== B) ----
    if (!fail) {
#pragma unroll
        for (int j = 0; j < NCAND; ++j) {
            if (cv[j] > 0.f) {
                const int bk = (int)(__float_as_uint(cv[j]) >> 20);
                if (bk > B) {
                    const int p = atomicAdd(&nDef, 1);
                    poolv[p] = cv[j]; pooli[p] = ci[j];
                } else if (bk == B) {
                    const int p = atomicAdd(&nBnd, 1);
                    if (p < BNDCAP) { poolv[C_SEL + p] = cv[j]; pooli[C_SEL + p] = ci[j]; }
                }
            }
        }
    } else {
        for (int i = 0; i < QPT; ++i) {
            const float4 v = *(const float4*)(&zr[(size_t)(t + i * TB) * 4]);
            const int base = (t + i * TB) * 4;
#define COL(f, o) { const unsigned uu = __float_as_uint(f); if (uu) { const int bk = (int)(uu >> 20); \
            if (bk > B) { const int p = atomicAdd(&nDef, 1); poolv[p] = (f); pooli[p] = base + o; } \
            else if (bk == B) { const int p = atomicAdd(&nBnd, 1); if (p < BNDCAP) { poolv[C_SEL + p] = (f); pooli[C_SEL + p] = base + o; } } } }
            COL(v.x, 0) COL(v.y, 1) COL(v.z, 2) COL(v.w, 3)
#undef COL
        }
    }
    __syncthreads();

    // ---- pad pool; init selv ----
    {
        const int ndef  = nDef;
        const int nbndc = (nBnd < BNDCAP) ? nBnd : BNDCAP;
        for (int i = t; i < POOLN; i += TB)
            if (!(i < ndef) && !(i >= C_SEL && i < C_SEL + nbndc)) { poolv[i] = NEGF; pooli[i] = BADIDX; }
        if (t < C_SEL) { selv[t] = NEGF; seli[t] = BADIDX; }
    }
    __syncthreads();

    // ---- rank-based top-40 by (value desc, index asc) ----
    for (int e = t; e < POOLN; e += TB) {
        const float mv = poolv[e]; const int mi = pooli[e];
        int rank = 0;
        for (int j = 0; j < POOLN; ++j) {
            const float vj = poolv[j]; const int ij = pooli[j];
            if (vj > mv || (vj == mv && ij < mi)) ++rank;
        }
        if (rank < C_SEL && mi != BADIDX) { selv[rank] = mv; seli[rank] = mi; }
    }
    __syncthreads();

    // ---- fp64 refine when rank-32/33 boundary is tight ----
    if (selv[K_TOP - 1] - selv[K_TOP] < DELTA) {
        const int l = t & 63;
        for (int k = t; k < D_IN; k += TB) xrow[k] = x[(size_t)row * D_IN + k] - b_dec[k];
        __syncthreads();
        for (int j = w; j < C_SEL; j += 4) {
            const int c = seli[j];
            if (c < D_SAE) {
                double acc = 0.0;
#pragma unroll
                for (int q = 0; q < D_IN / 64; ++q) {
                    const int k = l + q * 64;
                    acc = fma((double)xrow[k], (double)W_enc[(size_t)k * D_SAE + c], acc);
                }
#pragma unroll
                for (int off = 32; off > 0; off >>= 1) acc += __shfl_down(acc, off);
                if (l == 0) {
                    const double vv = acc + (double)b_enc[c];
                    cand[j] = vv > 0.0 ? vv : 0.0;
                }
            } else if (l == 0) cand[j] = -1e300;
        }
        __syncthreads();
        if (t == 0) {
            bool used[C_SEL]; float nv[K_TOP]; int ni[K_TOP];
            for (int j = 0; j < C_SEL; ++j) used[j] = false;
            for (int s = 0; s < K_TOP; ++s) {
                int bj = -1; double bvv = 0.0; int bidx = 0;
                for (int j = 0; j < C_SEL; ++j) {
                    if (used[j]) continue;
                    const double v = cand[j]; const int idx = seli[j];
                    if (bj < 0 || v > bvv || (v == bvv && idx < bidx)) { bj = j; bvv = v; bidx = idx; }
                }
                used[bj] = true; nv[s] = (float)bvv; ni[s] = bidx;
            }
            for (int s = 0; s < K_TOP; ++s) { selv[s] = nv[s]; seli[s] = ni[s]; }
        }
        __syncthreads();
    }

    // ---- write sparse row: zeros + scatter ----
    {
        const f32x4 z4 = (f32x4){0.f, 0.f, 0.f, 0.f};
        for (int i = 0; i < QPT; ++i)
            __builtin_nontemporal_store(z4, (f32x4*)(&zr[(size_t)(t + i * TB) * 4]));
    }
    __syncthreads();
    if (t < K_TOP && seli[t] < D_SAE) zr[seli[t]] = selv[t];

    // ---- decode ----
    float a0 = b_dec[t], a1 = b_dec[t + 256], a2 = b_dec[t + 512];
#pragma unroll 8
    for (int s = 0; s < K_TOP; ++s) {
        if (seli[s] < D_SAE) {
            const float v = selv[s];
            const float* wd = W_dec + (size_t)seli[s] * D_IN;
            a0 = fmaf(v, wd[t],       a0);
            a1 = fmaf(v, wd[t + 256], a1);
            a2 = fmaf(v, wd[t + 512], a2);
        }
    }
    float* xr = x_rec + (size_t)row * D_IN;
    xr[t] = a0; xr[t + 256] = a1; xr[t + 512] = a2;
}

extern "C" void kernel_launch(void* const* d_in, const int* in_sizes, int n_in,
                              void* d_out, int out_size, void* d_ws, size_t ws_size,
                              hipStream_t stream)
{
    const float* x     = (const float*)d_in[0];
    const float* W_enc = (const float*)d_in[1];
    const float* b_enc = (const float*)d_in[2];
    const float* W_dec = (const float*)d_in[3];
    const float* b_dec = (const float*)d_in[4];

    float* out   = (float*)d_out;
    float* x_rec = out;
    float* z     = out + (size_t)N_ROWS * D_IN;

    const size_t nA = (size_t)N_ROWS * D_IN;
    const size_t nB = (size_t)D_SAE * D_IN;
    const size_t need = (2 * nA + 2 * nB) * sizeof(ushort);

    if (ws_size >= need) {
        ushort* ahi = (ushort*)d_ws;
        ushort* alo = ahi + nA;
        ushort* bhi = alo + nA;
        ushort* blo = bhi + nB;
        sae_cvt_x<<<(int)(nA / 4 / 256), 256, 0, stream>>>(x, b_dec, ahi, alo);
        sae_cvt_w<<<dim3(D_SAE / 32, D_IN / 32), 256, 0, stream>>>(W_enc, bhi, blo);
        dim3 g1(N_ROWS / GBM, D_SAE / GBN);    // 64 x 128, row-blocks fast
        sae_encode_mfma3<<<g1, 256, 0, stream>>>(ahi, alo, bhi, blo, b_enc, z);
    } else {
        dim3 g0(D_SAE / GBN, N_ROWS / GBM);
        sae_encode_mfma<<<g0, 256, 0, stream>>>(x, W_enc, b_enc, b_dec, z);
    }
    sae_topk_decode<<<N_ROWS, TB, 0, stream>>>(z, x, W_enc, b_enc, W_dec, b_dec, x_rec);
}

// Round 18
// 1745.428 us; speedup vs baseline: 1.3525x; 1.2206x over previous
//
#include <hip/hip_runtime.h>

#define N_ROWS 8192
#define D_IN   768
#define D_SAE  24576
#define K_TOP  32
#define C_SEL  40
#define DELTA  2e-4f

typedef __attribute__((ext_vector_type(8))) short bf16x8;
typedef __attribute__((ext_vector_type(4))) float f32x4;

__device__ __forceinline__ ushort f2bf(float f) {
    const unsigned u = __float_as_uint(f);
    return (ushort)((u + 0x7FFFu + ((u >> 16) & 1u)) >> 16);
}
__device__ __forceinline__ float bf2f(ushort h) {
    return __uint_as_float(((unsigned)h) << 16);
}

#define GBM 128
#define GBN 192
#define GBK 32
#define SWZ(n) ((((n) >> 2) ^ (n)) & 3)

// ---------------- pre-pass 1: split (x - b_dec) into hi/lo bf16 planes ----------------
__global__ __launch_bounds__(256)
void sae_cvt_x(const float* __restrict__ x, const float* __restrict__ b_dec,
               ushort* __restrict__ ahi, ushort* __restrict__ alo)
{
    const int idx = blockIdx.x * 256 + threadIdx.x;
    const int i   = idx * 4;
    const int k   = (idx % (D_IN / 4)) * 4;
    const float4 xv = *(const float4*)(&x[i]);
    const float4 bd = *(const float4*)(&b_dec[k]);
    const float e[4] = {xv.x - bd.x, xv.y - bd.y, xv.z - bd.z, xv.w - bd.w};
    ushort h[4], l[4];
#pragma unroll
    for (int j = 0; j < 4; ++j) {
        h[j] = f2bf(e[j]);
        l[j] = f2bf(e[j] - bf2f(h[j]));
    }
    *(ushort4*)(&ahi[i]) = make_ushort4(h[0], h[1], h[2], h[3]);
    *(ushort4*)(&alo[i]) = make_ushort4(l[0], l[1], l[2], l[3]);
}

// ---------------- pre-pass 2: transpose W_enc [768][24576] -> [24576][768], split hi/lo ----------------
__global__ __launch_bounds__(256)
void sae_cvt_w(const float* __restrict__ W_enc,
               ushort* __restrict__ bhi, ushort* __restrict__ blo)
{
    __shared__ float tile[32][33];
    const int n0 = blockIdx.x * 32;
    const int k0 = blockIdx.y * 32;
    const int t  = threadIdx.x;
    const int r  = t >> 3;
    const int c4 = (t & 7) * 4;
    *(float4*)(&tile[r][c4]) = *(const float4*)(&W_enc[(size_t)(k0 + r) * D_SAE + n0 + c4]);
    __syncthreads();
    ushort h[4], l[4];
#pragma unroll
    for (int j = 0; j < 4; ++j) {
        const float e = tile[c4 + j][r];
        h[j] = f2bf(e);
        l[j] = f2bf(e - bf2f(h[j]));
    }
    *(ushort4*)(&bhi[(size_t)(n0 + r) * D_IN + k0 + c4]) = make_ushort4(h[0], h[1], h[2], h[3]);
    *(ushort4*)(&blo[(size_t)(n0 + r) * D_IN + k0 + c4]) = make_ushort4(l[0], l[1], l[2], l[3]);
}

// ------- GEMM: COALESCED staging (16 rows x 64B per quantum), XOR-swizzled LDS slots -------
// lane = 4*r4+c reads row grp*16+r4, chunk c -> 16 contiguous 64B segments per instruction
// LDS [pl][row][slot][8], slot = c ^ SWZ(row): writes conflict-free, frag reads 2-way (free)
__global__ __launch_bounds__(256, 2)
void sae_encode_mfma3(const ushort* __restrict__ ahi, const ushort* __restrict__ alo,
                      const ushort* __restrict__ bhi, const ushort* __restrict__ blo,
                      const float* __restrict__ b_enc, float* __restrict__ z)
{
    __shared__ ushort A_lds[2][GBM][4][8];   // 16 KB
    __shared__ ushort B_lds[2][GBN][4][8];   // 24 KB -> 40 KB total

    const int tid  = threadIdx.x;
    const int lane = tid & 63;
    const int wid  = tid >> 6;
    const int wr   = wid >> 1;
    const int wc   = wid & 1;
    const int l15  = lane & 15;
    const int lc   = lane >> 4;
    const int r4   = lane >> 2;       // 0..15 (staging row-in-group)
    const int cc   = lane & 3;        // 0..3  (staging k-chunk)

    const int col0  = blockIdx.y * GBN;       // row-blocks fast (L2 B-panel reuse)
    const int arow0 = blockIdx.x * GBM;
    const int row_w = arow0 + wr * 64;

    const int NT = D_IN / GBK;   // 24

    f32x4 acc[4][6];
#pragma unroll
    for (int i = 0; i < 4; ++i)
#pragma unroll
        for (int j = 0; j < 6; ++j) acc[i][j] = (f32x4){0.f, 0.f, 0.f, 0.f};

    bf16x8 s0, s1, s2, s3, s4, s5, s6, s7, s8, s9;

#define LOADQ(J, DST) { \
        const int q = (J) * 4 + wid; \
        if ((J) < 4) { \
            const int pl = q & 1, grp = q >> 1;            /* grp 0..7 */ \
            const int rowl = grp * 16 + r4; \
            DST = *(const bf16x8*)((pl ? alo : ahi) + (size_t)(arow0 + rowl) * D_IN + k0s + cc * 8); \
        } else { \
            const int r2 = q - 16; \
            const int pl = r2 & 1, grp = r2 >> 1;          /* grp 0..11 */ \
            const int rowl = grp * 16 + r4; \
            DST = *(const bf16x8*)((pl ? blo : bhi) + (size_t)(col0 + rowl) * D_IN + k0s + cc * 8); \
        } }

#define WRITEQ(J, SRC) { \
        const int q = (J) * 4 + wid; \
        if ((J) < 4) { \
            const int pl = q & 1, grp = q >> 1; \
            const int rowl = grp * 16 + r4; \
            *(bf16x8*)(&A_lds[pl][rowl][cc ^ SWZ(rowl)][0]) = SRC; \
        } else { \
            const int r2 = q - 16; \
            const int pl = r2 & 1, grp = r2 >> 1; \
            const int rowl = grp * 16 + r4; \
            *(bf16x8*)(&B_lds[pl][rowl][cc ^ SWZ(rowl)][0]) = SRC; \
        } }

#define LOAD_ALL() { LOADQ(0, s0) LOADQ(1, s1) LOADQ(2, s2) LOADQ(3, s3) LOADQ(4, s4) \
                     LOADQ(5, s5) LOADQ(6, s6) LOADQ(7, s7) LOADQ(8, s8) LOADQ(9, s9) }
#define WRITE_ALL() { WRITEQ(0, s0) WRITEQ(1, s1) WRITEQ(2, s2) WRITEQ(3, s3) WRITEQ(4, s4) \
                      WRITEQ(5, s5) WRITEQ(6, s6) WRITEQ(7, s7) WRITEQ(8, s8) WRITEQ(9, s9) }

    // prologue: load tile 0 into regs
    {
        const int k0s = 0;
        LOAD_ALL();
    }

    for (int kt = 0; kt < NT; ++kt) {
        WRITE_ALL();            // vmcnt drain for this tile's loads happens here
        __syncthreads();        // tile visible

        if (kt + 1 < NT) {
            const int k0s = (kt + 1) * GBK;
            LOAD_ALL();         // issue next tile's loads; in flight during MFMAs
        }

        bf16x8 bh[6], bl[6];
#pragma unroll
        for (int ct = 0; ct < 6; ++ct) {
            const int n = wc * 96 + ct * 16 + l15;
            const int sl = lc ^ SWZ(n);
            bh[ct] = *(const bf16x8*)(&B_lds[0][n][sl][0]);
            bl[ct] = *(const bf16x8*)(&B_lds[1][n][sl][0]);
        }
#pragma unroll
        for (int rt = 0; rt < 4; ++rt) {
            const int m = wr * 64 + rt * 16 + l15;
            const int sl = lc ^ SWZ(m);
            const bf16x8 ah = *(const bf16x8*)(&A_lds[0][m][sl][0]);
            const bf16x8 al = *(const bf16x8*)(&A_lds[1][m][sl][0]);
#pragma unroll
            for (int ct = 0; ct < 6; ++ct) {
                acc[rt][ct] = __builtin_amdgcn_mfma_f32_16x16x32_bf16(ah, bh[ct], acc[rt][ct], 0, 0, 0);
                acc[rt][ct] = __builtin_amdgcn_mfma_f32_16x16x32_bf16(ah, bl[ct], acc[rt][ct], 0, 0, 0);
                acc[rt][ct] = __builtin_amdgcn_mfma_f32_16x16x32_bf16(al, bh[ct], acc[rt][ct], 0, 0, 0);
            }
        }
        __syncthreads();        // reads done before next WRITE_ALL overwrites
    }

#undef LOAD_ALL
#undef WRITE_ALL
#undef LOADQ
#undef WRITEQ

    // ---- epilogue: + b_enc, relu, store ----
#pragma unroll
    for (int ct = 0; ct < 6; ++ct) {
        const int col = col0 + wc * 96 + ct * 16 + l15;
        const float bec = b_enc[col];
#pragma unroll
        for (int rt = 0; rt < 4; ++rt) {
            const int rowb = row_w + rt * 16 + lc * 4;
#pragma unroll
            for (int r = 0; r < 4; ++r)
                z[(size_t)(rowb + r) * D_SAE + col] = fmaxf(acc[rt][ct][r] + bec, 0.f);
        }
    }
}

// ---------------- fallback GEMM (conversion in-kernel), used if ws too small ----------------
__global__ __launch_bounds__(256, 2)
void sae_encode_mfma(const float* __restrict__ x,
                     const float* __restrict__ W_enc,
                     const float* __restrict__ b_enc,
                     const float* __restrict__ b_dec,
                     float* __restrict__ z)
{
    __shared__ ushort Bs[2][4][GBN][8];

    const int tid  = threadIdx.x;
    const int lane = tid & 63;
    const int wid  = tid >> 6;
    const int wr   = wid >> 1;
    const int wc   = wid & 1;
    const int l15  = lane & 15;
    const int lc   = lane >> 4;

    const int col0  = blockIdx.x * GBN;
    const int row_w = blockIdx.y * GBM + wr * 64;

    f32x4 acc[4][6];
#pragma unroll
    for (int i = 0; i < 4; ++i)
#pragma unroll
        for (int j = 0; j < 6; ++j) acc[i][j] = (f32x4){0.f, 0.f, 0.f, 0.f};

    for (int kt = 0; kt < D_IN / GBK; ++kt) {
        const int k0 = kt * GBK;

        float bvv[3][8];
#pragma unroll
        for (int np = 0; np < 3; ++np)
#pragma unroll
            for (int it = 0; it < 8; ++it)
                bvv[np][it] = W_enc[(size_t)(k0 + wid * 8 + it) * D_SAE + col0 + np * 64 + lane];

        const float4 bd0 = *(const float4*)(&b_dec[k0 + lc * 8]);
        const float4 bd1 = *(const float4*)(&b_dec[k0 + lc * 8 + 4]);
        bf16x8 ah[4], al[4];
#pragma unroll
        for (int rt = 0; rt < 4; ++rt) {
            const size_t off = (size_t)(row_w + rt * 16 + l15) * D_IN + k0 + lc * 8;
            const float4 a0 = *(const float4*)(&x[off]);
            const float4 a1 = *(const float4*)(&x[off + 4]);
            float e[8];
            e[0] = a0.x - bd0.x; e[1] = a0.y - bd0.y; e[2] = a0.z - bd0.z; e[3] = a0.w - bd0.w;
            e[4] = a1.x - bd1.x; e[5] = a1.y - bd1.y; e[6] = a1.z - bd1.z; e[7] = a1.w - bd1.w;
#pragma unroll
            for (int j = 0; j < 8; ++j) {
                const ushort h = f2bf(e[j]);
                ah[rt][j] = (short)h;
                al[rt][j] = (short)f2bf(e[j] - bf2f(h));
            }
        }

        uint4 bh_pk[3], bl_pk[3];
#pragma unroll
        for (int np = 0; np < 3; ++np) {
            ushort h[8], l[8];
#pragma unroll
            for (int it = 0; it < 8; ++it) {
                h[it] = f2bf(bvv[np][it]);
                l[it] = f2bf(bvv[np][it] - bf2f(h[it]));
            }
            bh_pk[np] = make_uint4((unsigned)h[0] | ((unsigned)h[1] << 16),
                                   (unsigned)h[2] | ((unsigned)h[3] << 16),
                                   (unsigned)h[4] | ((unsigned)h[5] << 16),
                                   (unsigned)h[6] | ((unsigned)h[7] << 16));
            bl_pk[np] = make_uint4((unsigned)l[0] | ((unsigned)l[1] << 16),
                                   (unsigned)l[2] | ((unsigned)l[3] << 16),
                                   (unsigned)l[4] | ((unsigned)l[5] << 16),
                                   (unsigned)l[6] | ((unsigned)l[7] << 16));
        }

        __syncthreads();
#pragma unroll
        for (int np = 0; np < 3; ++np) {
            const int n = np * 64 + lane;
            *(uint4*)(&Bs[0][wid][n][0]) = bh_pk[np];
            *(uint4*)(&Bs[1][wid][n][0]) = bl_pk[np];
        }
        __syncthreads();

#pragma unroll
        for (int ct = 0; ct < 6; ++ct) {
            const int n = wc * 96 + ct * 16 + l15;
            const bf16x8 bh = *(const bf16x8*)(&Bs[0][lc][n][0]);
            const bf16x8 bl = *(const bf16x8*)(&Bs[1][lc][n][0]);
#pragma unroll
            for (int rt = 0; rt < 4; ++rt) {
                acc[rt][ct] = __builtin_amdgcn_mfma_f32_16x16x32_bf16(ah[rt], bh, acc[rt][ct], 0, 0, 0);
                acc[rt][ct] = __builtin_amdgcn_mfma_f32_16x16x32_bf16(ah[rt], bl, acc[rt][ct], 0, 0, 0);
                acc[rt][ct] = __builtin_amdgcn_mfma_f32_16x16x32_bf16(al[rt], bh, acc[rt][ct], 0, 0, 0);
            }
        }
    }

#pragma unroll
    for (int ct = 0; ct < 6; ++ct) {
        const int col = col0 + wc * 96 + ct * 16 + l15;
        const float bec = b_enc[col];
#pragma unroll
        for (int rt = 0; rt < 4; ++rt) {
            const int rowb = row_w + rt * 16 + lc * 4;
#pragma unroll
            for (int r = 0; r < 4; ++r)
                z[(size_t)(rowb + r) * D_SAE + col] = fmaxf(acc[rt][ct][r] + bec, 0.f);
        }
    }
}

// ------- per-row: candidate-only histogram, rank-select, sparsify, decode -------
#define TB     256
#define QPT    (D_SAE / 4 / TB)   // 24
#define HB     2048
#define NCOPY  2
#define BNDCAP 248
#define POOLN  288                // C_SEL + BNDCAP
#define NCAND  6
#define NEGF   -1e30f
#define BADIDX (1 << 30)

__global__ __launch_bounds__(TB, 4)
void sae_topk_decode(float* __restrict__ z,
                     const float* __restrict__ x,
                     const float* __restrict__ W_enc,
                     const float* __restrict__ b_enc,
                     const float* __restrict__ W_dec,
                     const float* __restrict__ b_dec,
                     float* __restrict__ x_rec)
{
    __shared__ int    hist[NCOPY * HB];   // 16 KB
    __shared__ int    sufx[TB];
    __shared__ float  poolv[POOLN];
    __shared__ int    pooli[POOLN];
    __shared__ float  selv[C_SEL];
    __shared__ int    seli[C_SEL];
    __shared__ float  xrow[D_IN];
    __shared__ double cand[C_SEL];
    __shared__ int    shB;
    __shared__ int    nDef, nBnd, nFail;

    const int row = blockIdx.x;
    const int t   = threadIdx.x;
    const int w   = t >> 6;
    float* zr = z + (size_t)row * D_SAE;
    int* hw = &hist[(w >> 1) * HB];

    for (int i = t; i < NCOPY * HB; i += TB) hist[i] = 0;
    if (t == 0) { nDef = 0; nBnd = 0; nFail = 0; }
    __syncthreads();

    // ---- phase 1: single streaming read; per-thread top-6 candidates (NO atomics) ----
    float cv[NCAND]; int ci[NCAND];
#pragma unroll
    for (int j = 0; j < NCAND; ++j) { cv[j] = NEGF; ci[j] = BADIDX; }
    {
        for (int i0 = 0; i0 < QPT; i0 += 8) {
            f32x4 va[8];
#pragma unroll
            for (int u2 = 0; u2 < 8; ++u2)
                va[u2] = __builtin_nontemporal_load((const f32x4*)(&zr[(size_t)(t + (i0 + u2) * TB) * 4]));
#pragma unroll
            for (int u2 = 0; u2 < 8; ++u2) {
                const int base = (t + (i0 + u2) * TB) * 4;
#define PROC(f, o) { \
        const bool b0 = (f) > cv[0]; const bool b1 = (f) > cv[1]; const bool b2 = (f) > cv[2]; \
        const bool b3 = (f) > cv[3]; const bool b4 = (f) > cv[4]; const bool b5 = (f) > cv[5]; \
        if (b5) { \
            cv[5] = b4 ? cv[4] : (f);        ci[5] = b4 ? ci[4] : (base + o); \
            if (b4) { cv[4] = b3 ? cv[3] : (f); ci[4] = b3 ? ci[3] : (base + o); } \
            if (b3) { cv[3] = b2 ? cv[2] : (f); ci[3] = b2 ? ci[2] : (base + o); } \
            if (b2) { cv[2] = b1 ? cv[1] : (f); ci[2] = b1 ? ci[1] : (base + o); } \
            if (b1) { cv[1] = b0 ? cv[0] : (f); ci[1] = b0 ? ci[0] : (base + o); } \
            if (b0) { cv[0] = (f); ci[0] = (base + o); } \
        } }
                PROC(va[u2][0], 0) PROC(va[u2][1], 1) PROC(va[u2][2], 2) PROC(va[u2][3], 3)
#undef PROC
            }
        }
    }

    // ---- phase 2: histogram the 6 candidates per thread ----
#pragma unroll
    for (int j = 0; j < NCAND; ++j)
        atomicAdd(&hw[__float_as_uint(cv[j]) >> 20], 1);
    __syncthreads();

    // ---- find threshold bucket B over candidate counts ----
    {
        int cnt8[8]; int tot = 0;
#pragma unroll
        for (int j = 0; j < 8; ++j) {
            const int b = t * 8 + j;
            const int c = hist[b] + hist[HB + b];
            cnt8[j] = c; tot += c;
        }
        sufx[t] = tot;
        __syncthreads();
        for (int off = 1; off < TB; off <<= 1) {
            const int a = sufx[t];
            const int b = (t + off < TB) ? sufx[t + off] : 0;
            __syncthreads();
            sufx[t] = a + b;
            __syncthreads();
        }
        int run = (t + 1 < TB) ? sufx[t + 1] : 0;
#pragma unroll
        for (int j = 7; j >= 0; --j) {
            const int c = cnt8[j];
            if (run < C_SEL && run + c >= C_SEL) shB = t * 8 + j;
            run += c;
        }
    }
    __syncthreads();

    // ---- fail check ----
    if (cv[NCAND - 1] > 0.f && (int)(__float_as_uint(cv[NCAND - 1]) >> 20) >= shB) nFail = 1;
    __syncthreads();
    const bool fail = (nFail != 0);

    if (fail) {
        for (int i = t; i < NCOPY * HB; i += TB) hist[i] = 0;
        __syncthreads();
        for (int i = 0; i < QPT; ++i) {
            const float4 v = *(const float4*)(&zr[(size_t)(t + i * TB) * 4]);
            atomicAdd(&hw[__float_as_uint(v.x) >> 20], 1);
            atomicAdd(&hw[__float_as_uint(v.y) >> 20], 1);
            atomicAdd(&hw[__float_as_uint(v.z) >> 20], 1);
            atomicAdd(&hw[__float_as_uint(v.w) >> 20], 1);
        }
        __syncthreads();
        int cnt8[8]; int tot = 0;
#pragma unroll
        for (int j = 0; j < 8; ++j) {
            const int b = t * 8 + j;
            const int c = hist[b] + hist[HB + b];
            cnt8[j] = c; tot += c;
        }
        sufx[t] = tot;
        __syncthreads();
        for (int off = 1; off < TB; off <<= 1) {
            const int a = sufx[t];
            const int b = (t + off < TB) ? sufx[t + off] : 0;
            __syncthreads();
            sufx[t] = a + b;
            __syncthreads();
        }
        int run = (t + 1 < TB) ? sufx[t + 1] : 0;
#pragma unroll
        for (int j = 7; j >= 0; --j) {
            const int c = cnt8[j];
            if (run < C_SEL && run + c >= C_SEL) shB = t * 8 + j;
            run += c;
        }
        __syncthreads();
    }
    const int B = shB;

    // ---- collect: defs (bucket > B) and boundary (== B) ----
    if (!fail) {
#pragma unroll
        for (int j = 0; j < NCAND; ++j) {
            if (cv[j] > 0.f) {
                const int bk = (int)(__float_as_uint(cv[j]) >> 20);
                if (bk > B) {
                    const int p = atomicAdd(&nDef, 1);
                    poolv[p] = cv[j]; pooli[p] = ci[j];
                } else if (bk == B) {
                    const int p = atomicAdd(&nBnd, 1);
                    if (p < BNDCAP) { poolv[C_SEL + p] = cv[j]; pooli[C_SEL + p] = ci[j]; }
                }
            }
        }
    } else {
        for (int i = 0; i < QPT; ++i) {
            const float4 v = *(const float4*)(&zr[(size_t)(t + i * TB) * 4]);
            const int base = (t + i * TB) * 4;
#define COL(f, o) { const unsigned uu = __float_as_uint(f); if (uu) { const int bk = (int)(uu >> 20); \
            if (bk > B) { const int p = atomicAdd(&nDef, 1); poolv[p] = (f); pooli[p] = base + o; } \
            else if (bk == B) { const int p = atomicAdd(&nBnd, 1); if (p < BNDCAP) { poolv[C_SEL + p] = (f); pooli[C_SEL + p] = base + o; } } } }
            COL(v.x, 0) COL(v.y, 1) COL(v.z, 2) COL(v.w, 3)
#undef COL
        }
    }
    __syncthreads();

    // ---- pad pool; init selv ----
    {
        const int ndef  = nDef;
        const int nbndc = (nBnd < BNDCAP) ? nBnd : BNDCAP;
        for (int i = t; i < POOLN; i += TB)
            if (!(i < ndef) && !(i >= C_SEL && i < C_SEL + nbndc)) { poolv[i] = NEGF; pooli[i] = BADIDX; }
        if (t < C_SEL) { selv[t] = NEGF; seli[t] = BADIDX; }
    }
    __syncthreads();

    // ---- rank-based top-40 by (value desc, index asc) ----
    for (int e = t; e < POOLN; e += TB) {
        const float mv = poolv[e]; const int mi = pooli[e];
        int rank = 0;
        for (int j = 0; j < POOLN; ++j) {
            const float vj = poolv[j]; const int ij = pooli[j];
            if (vj > mv || (vj == mv && ij < mi)) ++rank;
        }
        if (rank < C_SEL && mi != BADIDX) { selv[rank] = mv; seli[rank] = mi; }
    }
    __syncthreads();

    // ---- fp64 refine when rank-32/33 boundary is tight ----
    if (selv[K_TOP - 1] - selv[K_TOP] < DELTA) {
        const int l = t & 63;
        for (int k = t; k < D_IN; k += TB) xrow[k] = x[(size_t)row * D_IN + k] - b_dec[k];
        __syncthreads();
        for (int j = w; j < C_SEL; j += 4) {
            const int c = seli[j];
            if (c < D_SAE) {
                double acc = 0.0;
#pragma unroll
                for (int q = 0; q < D_IN / 64; ++q) {
                    const int k = l + q * 64;
                    acc = fma((double)xrow[k], (double)W_enc[(size_t)k * D_SAE + c], acc);
                }
#pragma unroll
                for (int off = 32; off > 0; off >>= 1) acc += __shfl_down(acc, off);
                if (l == 0) {
                    const double vv = acc + (double)b_enc[c];
                    cand[j] = vv > 0.0 ? vv : 0.0;
                }
            } else if (l == 0) cand[j] = -1e300;
        }
        __syncthreads();
        if (t == 0) {
            bool used[C_SEL]; float nv[K_TOP]; int ni[K_TOP];
            for (int j = 0; j < C_SEL; ++j) used[j] = false;
            for (int s = 0; s < K_TOP; ++s) {
                int bj = -1; double bvv = 0.0; int bidx = 0;
                for (int j = 0; j < C_SEL; ++j) {
                    if (used[j]) continue;
                    const double v = cand[j]; const int idx = seli[j];
                    if (bj < 0 || v > bvv || (v == bvv && idx < bidx)) { bj = j; bvv = v; bidx = idx; }
                }
                used[bj] = true; nv[s] = (float)bvv; ni[s] = bidx;
            }
            for (int s = 0; s < K_TOP; ++s) { selv[s] = nv[s]; seli[s] = ni[s]; }
        }
        __syncthreads();
    }

    // ---- write sparse row: zeros + scatter ----
    {
        const f32x4 z4 = (f32x4){0.f, 0.f, 0.f, 0.f};
        for (int i = 0; i < QPT; ++i)
            __builtin_nontemporal_store(z4, (f32x4*)(&zr[(size_t)(t + i * TB) * 4]));
    }
    __syncthreads();
    if (t < K_TOP && seli[t] < D_SAE) zr[seli[t]] = selv[t];

    // ---- decode ----
    float a0 = b_dec[t], a1 = b_dec[t + 256], a2 = b_dec[t + 512];
#pragma unroll 8
    for (int s = 0; s < K_TOP; ++s) {
        if (seli[s] < D_SAE) {
            const float v = selv[s];
            const float* wd = W_dec + (size_t)seli[s] * D_IN;
            a0 = fmaf(v, wd[t],       a0);
            a1 = fmaf(v, wd[t + 256], a1);
            a2 = fmaf(v, wd[t + 512], a2);
        }
    }
    float* xr = x_rec + (size_t)row * D_IN;
    xr[t] = a0; xr[t + 256] = a1; xr[t + 512] = a2;
}

extern "C" void kernel_launch(void* const* d_in, const int* in_sizes, int n_in,
                              void* d_out, int out_size, void* d_ws, size_t ws_size,
                              hipStream_t stream)
{
    const float* x     = (const float*)d_in[0];
    const float* W_enc = (const float*)d_in[1];
    const float* b_enc = (const float*)d_in[2];
    const float* W_dec = (const float*)d_in[3];
    const float* b_dec = (const float*)d_in[4];

    float* out   = (float*)d_out;
    float* x_rec = out;
    float* z     = out + (size_t)N_ROWS * D_IN;

    const size_t nA = (size_t)N_ROWS * D_IN;
    const size_t nB = (size_t)D_SAE * D_IN;
    const size_t need = (2 * nA + 2 * nB) * sizeof(ushort);

    if (ws_size >= need) {
        ushort* ahi = (ushort*)d_ws;
        ushort* alo = ahi + nA;
        ushort* bhi = alo + nA;
        ushort* blo = bhi + nB;
        sae_cvt_x<<<(int)(nA / 4 / 256), 256, 0, stream>>>(x, b_dec, ahi, alo);
        sae_cvt_w<<<dim3(D_SAE / 32, D_IN / 32), 256, 0, stream>>>(W_enc, bhi, blo);
        dim3 g1(N_ROWS / GBM, D_SAE / GBN);    // 64 x 128, row-blocks fast
        sae_encode_mfma3<<<g1, 256, 0, stream>>>(ahi, alo, bhi, blo, b_enc, z);
    } else {
        dim3 g0(D_SAE / GBN, N_ROWS / GBM);
        sae_encode_mfma<<<g0, 256, 0, stream>>>(x, W_enc, b_enc, b_dec, z);
    }
    sae_topk_decode<<<N_ROWS, TB, 0, stream>>>(z, x, W_enc, b_enc, W_dec, b_dec, x_rec);
}